// Round 4
// baseline (123.322 us; speedup 1.0000x reference)
//
#include <hip/hip_runtime.h>
#include <math.h>

// IF spiking layer, step == T. Two-phase split:
//   K1: per column j, n[j] = clamp(ceil((0.5*thr + sum_t x[t][j])/thr - 1), 0, T)
//       (f64 sequential sum + closed form — bit-identical to R2/R3, absmax 0)
//       counts written packed as uchar4 into d_ws (1 MB).
//   K2: linear sweep of the 264 MB output: out[t][j] = (t < n[j]) ? thr : 0.
// Rationale: fused kernel measured 4.49 TB/s (mixed 63-stream read + 63-stream
// write per wave). Harness fill kernel measures 7.0+ TB/s write-only. Splitting
// gives a pure-read phase and a fill-shaped pure-write phase.

static constexpr int T_STEPS = 63;

__global__ __launch_bounds__(256) void IF_count_kernel(const float4* __restrict__ x,
                                                       const float* __restrict__ alphap,
                                                       uchar4* __restrict__ counts,
                                                       int nvec) {
    int i = blockIdx.x * blockDim.x + threadIdx.x;
    if (i >= nvec) return;

    const double thr     = (double)alphap[0];
    const double inv_thr = 1.0 / thr;   // 0.125, exact

    // Sequential f64 sum over t (validated: absmax 0 in R2/R3).
    double sx = 0.0, sy = 0.0, sz = 0.0, sw = 0.0;
    const float4* xp = x + i;
    #pragma unroll 9
    for (int t = 0; t < T_STEPS; ++t) {
        float4 v = xp[(size_t)t * nvec];
        sx += (double)v.x; sy += (double)v.y; sz += (double)v.z; sw += (double)v.w;
    }

    auto count = [&](double s) -> unsigned char {
        double r = (0.5 * thr + s) * inv_thr - 1.0;   // exact ops (thr = 2^3)
        int n = (int)ceil(r);
        n = n < 0 ? 0 : (n > T_STEPS ? T_STEPS : n);
        return (unsigned char)n;
    };
    counts[i] = make_uchar4(count(sx), count(sy), count(sz), count(sw));
}

__global__ __launch_bounds__(256) void IF_emit_kernel(const uchar4* __restrict__ counts,
                                                      const float* __restrict__ alphap,
                                                      float4* __restrict__ out,
                                                      int nvec_log2, int total4) {
    const float thr_f = alphap[0];
    const int   jmask = (1 << nvec_log2) - 1;
    const int   stride = gridDim.x * blockDim.x;

    for (int idx = blockIdx.x * blockDim.x + threadIdx.x; idx < total4; idx += stride) {
        const int t = idx >> nvec_log2;        // slice
        const int j = idx & jmask;             // float4-column within slice
        const uchar4 c = counts[j];            // L2/L3-resident (1 MB total)
        float4 o;
        o.x = (t < (int)c.x) ? thr_f : 0.f;
        o.y = (t < (int)c.y) ? thr_f : 0.f;
        o.z = (t < (int)c.z) ? thr_f : 0.f;
        o.w = (t < (int)c.w) ? thr_f : 0.f;
        out[idx] = o;                          // perfectly linear store sweep
    }
}

extern "C" void kernel_launch(void* const* d_in, const int* in_sizes, int n_in,
                              void* d_out, int out_size, void* d_ws, size_t ws_size,
                              hipStream_t stream) {
    const float* x = (const float*)d_in[0];
    const float* alpha = (const float*)d_in[1];
    float* out = (float*)d_out;

    const int per_slice = in_sizes[0] / T_STEPS;   // B*S*D = 1048576
    const int nvec = per_slice / 4;                // 262144 float4 columns
    int nvec_log2 = 0;
    while ((1 << nvec_log2) < nvec) ++nvec_log2;   // 18

    uchar4* counts = (uchar4*)d_ws;                // nvec bytes = 1 MB scratch

    const int block = 256;
    const int grid1 = (nvec + block - 1) / block;  // 1024 blocks
    IF_count_kernel<<<grid1, block, 0, stream>>>((const float4*)x, alpha,
                                                 counts, nvec);

    const int total4 = out_size / 4;               // 16,515,072 float4 stores
    const int grid2 = 2048;                        // 8 blocks/CU, grid-stride
    IF_emit_kernel<<<grid2, block, 0, stream>>>(counts, alpha,
                                                (float4*)out, nvec_log2, total4);
}

// Round 6
// 80.585 us; speedup vs baseline: 1.5303x; 1.5303x over previous
//
#include <hip/hip_runtime.h>
#include <math.h>

// IF spiking layer, step == T. Two-phase:
//   K1 (read):  per float4-column j, n[j] = clamp(ceil((0.5*thr + sum_t x)/thr - 1), 0, T)
//               -> packed uchar4 counts in d_ws (1 MB). f64 sequential t-sum
//               (bit-matched the reference in R2-R4, absmax 0).
//   K2 (write): linear fill-shaped sweep: out[t][j] = (t < n[j]) ? thr : 0.
//
// R4 analysis: read phase sustained only ~3.3 TB/s because each wave issued
// 1 KB bursts at 4 MB stride (63 streams). Here each WAVE owns a 4 KB
// contiguous column span and issues 4 back-to-back dwordx4 loads per t-slice
// (4 KB sequential per stream visit), unroll 3 over t for ~12 loads in flight.
// Nontemporal loads use a native ext_vector type (builtin rejects HIP float4).

static constexpr int T_STEPS = 63;

typedef float fx4 __attribute__((ext_vector_type(4)));

__global__ __launch_bounds__(256) void IF_count_kernel(const fx4* __restrict__ x,
                                                       const float* __restrict__ alphap,
                                                       uchar4* __restrict__ counts,
                                                       int nvec) {
    const int wave = threadIdx.x >> 6;                    // 0..3
    const int lane = threadIdx.x & 63;
    const int wave_base = (blockIdx.x * 4 + wave) * 256;  // float4-column base of this wave

    const fx4* xw = x + wave_base;

    double acc[4][4];
    #pragma unroll
    for (int k = 0; k < 4; ++k)
        #pragma unroll
        for (int c = 0; c < 4; ++c) acc[k][c] = 0.0;

    #pragma unroll 3
    for (int t = 0; t < T_STEPS; ++t) {
        const fx4* xt = xw + (size_t)t * nvec;
        #pragma unroll
        for (int k = 0; k < 4; ++k) {
            fx4 v = __builtin_nontemporal_load(&xt[k * 64 + lane]);
            acc[k][0] += (double)v.x;
            acc[k][1] += (double)v.y;
            acc[k][2] += (double)v.z;
            acc[k][3] += (double)v.w;
        }
    }

    const double thr     = (double)alphap[0];
    const double inv_thr = 1.0 / thr;                     // 0.125, exact

    auto cnt = [&](double s) -> unsigned char {
        double r = (0.5 * thr + s) * inv_thr - 1.0;       // exact ops (thr = 2^3)
        int n = (int)ceil(r);
        n = n < 0 ? 0 : (n > T_STEPS ? T_STEPS : n);
        return (unsigned char)n;
    };

    #pragma unroll
    for (int k = 0; k < 4; ++k) {
        uchar4 c4;
        c4.x = cnt(acc[k][0]);
        c4.y = cnt(acc[k][1]);
        c4.z = cnt(acc[k][2]);
        c4.w = cnt(acc[k][3]);
        counts[wave_base + k * 64 + lane] = c4;
    }
}

__global__ __launch_bounds__(256) void IF_emit_kernel(const uchar4* __restrict__ counts,
                                                      const float* __restrict__ alphap,
                                                      float4* __restrict__ out,
                                                      int nvec_log2, int total4) {
    const float thr_f = alphap[0];
    const int   jmask = (1 << nvec_log2) - 1;
    const int   stride = gridDim.x * blockDim.x;

    for (int idx = blockIdx.x * blockDim.x + threadIdx.x; idx < total4; idx += stride) {
        const int t = idx >> nvec_log2;
        const int j = idx & jmask;
        const uchar4 c = counts[j];                       // L2-resident (1 MB)
        float4 o;
        o.x = (t < (int)c.x) ? thr_f : 0.f;
        o.y = (t < (int)c.y) ? thr_f : 0.f;
        o.z = (t < (int)c.z) ? thr_f : 0.f;
        o.w = (t < (int)c.w) ? thr_f : 0.f;
        out[idx] = o;                                     // linear store sweep
    }
}

extern "C" void kernel_launch(void* const* d_in, const int* in_sizes, int n_in,
                              void* d_out, int out_size, void* d_ws, size_t ws_size,
                              hipStream_t stream) {
    const float* x = (const float*)d_in[0];
    const float* alpha = (const float*)d_in[1];
    float* out = (float*)d_out;

    const int per_slice = in_sizes[0] / T_STEPS;   // 1048576 elements
    const int nvec = per_slice / 4;                // 262144 float4 columns
    int nvec_log2 = 0;
    while ((1 << nvec_log2) < nvec) ++nvec_log2;   // 18

    uchar4* counts = (uchar4*)d_ws;

    const int block = 256;
    const int grid1 = nvec / 1024;                 // 256 blocks (1024 cols/block)
    IF_count_kernel<<<grid1, block, 0, stream>>>((const fx4*)x, alpha,
                                                 counts, nvec);

    const int total4 = out_size / 4;               // 16,515,072 float4 stores
    const int grid2 = 2048;
    IF_emit_kernel<<<grid2, block, 0, stream>>>(counts, alpha,
                                                (float4*)out, nvec_log2, total4);
}